// Round 6
// baseline (300.711 us; speedup 1.0000x reference)
//
#include <hip/hip_runtime.h>
#include <hip/hip_bf16.h>
#include <math.h>

// EquivariantGraphConv fused kernel for MI355X (gfx950).
// B=2, N=512, D=HID=OUT=128.
//
// Structure (round 5): edge MLP factorized -- h1 = aw_i + Bbuf_j + dist*wd
// (precomputed per-node), and since there is no activation between the two
// edge GEMMs, c1 = s@M + bias2 with M = eW2@cW1 precomputed. Aggregation
// uses column-sums of s: Sum_j edge_hidden = (Sum_j s)@eW2 + 512*eb2.
//
// Round 5 -> 6: counters showed no spills (WRITE 552KB) but MfmaUtil 4.4% /
// VALUBusy 30% / Occupancy 24% -- latency-bound at ~2 blocks/CU with the
// Bbuf L2 loads exposed between barriers. Fixes:
//  (1) __launch_bounds__(256,4): 4 blocks/CU resident, VGPR cap 128.
//  (2) T14 register prefetch: issue next-tile Bbuf (8 x f32x4) + coords
//      loads right after Bar1; consume in next build phase. L2 latency
//      hides under GEMM+agg+coordw.
//  (3) f2bf via __float2bfloat16 (compiler packs cvt).

typedef float f32x4 __attribute__((ext_vector_type(4)));
typedef short short8 __attribute__((ext_vector_type(8)));

#define MFMA16(a, b, c) __builtin_amdgcn_mfma_f32_16x16x32_bf16((a), (b), (c), 0, 0, 0)

__device__ __forceinline__ short f2bf(float x) {
    __hip_bfloat16 h = __float2bfloat16(x);
    union { __hip_bfloat16 h; short s; } v; v.h = h;
    return v.s;
}
__device__ __forceinline__ float bf2f(short s) {
    union { unsigned u; float f; } v; v.u = ((unsigned)(unsigned short)s) << 16;
    return v.f;
}
__device__ __forceinline__ float silu_f(float x) {
    return x * __builtin_amdgcn_rcpf(1.0f + __expf(-x));
}

// XOR swizzle for [rows][128] bf16 LDS tiles (G4: break stride-256B conflicts).
__device__ __forceinline__ int swz(int row, int col) {
    int byte = (row << 8) | (col << 1);
    byte ^= (row & 7) << 4;
    return byte >> 1;  // bf16-element index
}

// ---------- precompute: Abuf = feat @ eW1[0:128] + eb1 ; Bbuf = feat @ eW1[128:256]
__global__ void egnn_pre(const float* __restrict__ feat, const float* __restrict__ eW1,
                         const float* __restrict__ eb1,
                         float* __restrict__ Abuf, float* __restrict__ Bbuf) {
    __shared__ float f[128];
    const int nid = blockIdx.x;
    const int t = threadIdx.x;   // 256 threads
    if (t < 128) f[t] = feat[nid * 128 + t];
    __syncthreads();
    const int col  = t & 127;
    const int half = t >> 7;
    const float* W = eW1 + (size_t)half * 128 * 128 + col;
    float acc = half ? 0.f : eb1[col];
    #pragma unroll 8
    for (int k = 0; k < 128; ++k) acc += f[k] * W[(size_t)k * 128];
    if (half == 0) Abuf[nid * 128 + col] = acc;
    else           Bbuf[nid * 128 + col] = acc;
}

// ---------- precompute: M = eW2 @ cW1 (128x128), bias2 = eb2 @ cW1 + cb1 (128)
__global__ void egnn_wprep(const float* __restrict__ eW2, const float* __restrict__ cW1,
                           const float* __restrict__ eb2, const float* __restrict__ cb1,
                           float* __restrict__ Mws, float* __restrict__ bias2ws) {
    const int a = blockIdx.x;      // 0..128 (128 => bias2)
    const int c = threadIdx.x;     // 128 threads
    if (a < 128) {
        float acc = 0.f;
        #pragma unroll 8
        for (int h = 0; h < 128; ++h) acc += eW2[a * 128 + h] * cW1[h * 128 + c];
        Mws[a * 128 + c] = acc;
    } else {
        float acc = cb1[c];
        #pragma unroll 8
        for (int h = 0; h < 128; ++h) acc += eb2[h] * cW1[h * 128 + c];
        bias2ws[c] = acc;
    }
}

// ---------- main fused kernel: one block per (b,i) node
__global__ void __launch_bounds__(256, 4) egnn_main(
    const float* __restrict__ features, const float* __restrict__ coords,
    const float* __restrict__ eW1, const float* __restrict__ eW2,
    const float* __restrict__ eb2,
    const float* __restrict__ nW1, const float* __restrict__ nb1,
    const float* __restrict__ nW2, const float* __restrict__ nb2,
    const float* __restrict__ cW2, const float* __restrict__ cb2,
    const float* __restrict__ Abuf, const float* __restrict__ Bbuf,
    const float* __restrict__ Mws, const float* __restrict__ bias2ws,
    float* __restrict__ out_feat, float* __restrict__ out_coord)
{
    constexpr int Nn = 512;
    __shared__ __align__(16) short se[64 * 128];            // 16 KB s-tile
    __shared__ float aw[128], wd[128];
    __shared__ float cdp[2][3][64];                         // parity-buffered coord diffs
    __shared__ float warr[2][4][64];                        // parity-buffered w partials
    __shared__ float aggw[2][128], aggs[128], aggh[128], hbuf[128];
    __shared__ float cred[4][3];
    __shared__ float ci3[3];

    const int tid  = threadIdx.x;
    const int lane = tid & 63;
    const int wave = tid >> 6;
    const int node = blockIdx.x;       // b*512 + i
    const int b    = node >> 9;

    if (tid < 128) {
        aw[tid] = Abuf[node * 128 + tid];      // includes eb1
        wd[tid] = eW1[256 * 128 + tid];        // distance row of eW1
    }
    if (tid == 0) {
        ci3[0] = coords[node * 3 + 0];
        ci3[1] = coords[node * 3 + 1];
        ci3[2] = coords[node * 3 + 2];
    }

    // ---- M^T fragments straight from global (L2-resident, prologue-once)
    const int cfrag = wave * 32 + (lane & 15);
    const int koff  = (lane >> 4) * 8;
    short8 wfM[2][4];
    #pragma unroll
    for (int n2 = 0; n2 < 2; ++n2)
        #pragma unroll
        for (int k = 0; k < 4; ++k) {
            short8 v;
            #pragma unroll
            for (int j = 0; j < 8; ++j)
                v[j] = f2bf(Mws[(k * 32 + koff + j) * 128 + cfrag + n2 * 16]);
            wfM[n2][k] = v;
        }
    __syncthreads();

    const float b2_0  = bias2ws[cfrag], b2_1 = bias2ws[cfrag + 16];
    const float cw2_0 = cW2[cfrag],     cw2_1 = cW2[cfrag + 16];
    const float cb2v  = cb2[0];
    const float cix = ci3[0], ciy = ci3[1], ciz = ci3[2];

    const int jr = tid >> 2, cb = (tid & 3) * 32;   // build mapping
    const int acol = tid & 127, agrp = tid >> 7;    // agg re-read mapping

    float aggp = 0.f;                   // per-thread partial of Sum_j s[j][acol]
    float cax = 0.f, cay = 0.f, caz = 0.f;

    // ---- prefetch tile 0 (Bbuf row chunk + neighbor coords) into registers
    f32x4 pf[8];
    float pcx, pcy, pcz;
    {
        const int j = jr;
        const float* Bj = Bbuf + (size_t)(b * Nn + j) * 128 + cb;
        #pragma unroll
        for (int ci = 0; ci < 8; ++ci) pf[ci] = *(const f32x4*)(Bj + ci * 4);
        pcx = coords[(b * Nn + j) * 3 + 0];
        pcy = coords[(b * Nn + j) * 3 + 1];
        pcz = coords[(b * Nn + j) * 3 + 2];
    }

    for (int t = 0; t < 8; ++t) {
        const int par = t & 1;
        // -- build: s = silu(aw + Bbuf_j + dist*wd) -> bf16 LDS (from prefetch regs)
        {
            const float dx = cix - pcx, dy = ciy - pcy, dz = ciz - pcz;
            const float dj = sqrtf(dx * dx + dy * dy + dz * dz + 1e-8f);
            if ((tid & 3) == 0) {
                cdp[par][0][jr] = dx; cdp[par][1][jr] = dy; cdp[par][2][jr] = dz;
            }
            #pragma unroll
            for (int cc = 0; cc < 32; cc += 8) {
                short8 v;
                #pragma unroll
                for (int r = 0; r < 8; ++r) {
                    const int c = cb + cc + r;
                    const float x = aw[c] + pf[cc / 4 + r / 4][r & 3] + dj * wd[c];
                    v[r] = f2bf(silu_f(x));
                }
                *(short8*)&se[swz(jr, cb + cc)] = v;
            }
        }
        __syncthreads();                                   // Bar1: tile ready

        // -- issue prefetch for tile t+1 (overlaps with GEMM/agg/coordw below)
        if (t < 7) {
            const int j = (t + 1) * 64 + jr;
            const float* Bj = Bbuf + (size_t)(b * Nn + j) * 128 + cb;
            #pragma unroll
            for (int ci = 0; ci < 8; ++ci) pf[ci] = *(const f32x4*)(Bj + ci * 4);
            pcx = coords[(b * Nn + j) * 3 + 0];
            pcy = coords[(b * Nn + j) * 3 + 1];
            pcz = coords[(b * Nn + j) * 3 + 2];
        }

        // -- GEMM: c1 = s @ M + bias2 (acc init = bias2)
        f32x4 acc[4][2];
        #pragma unroll
        for (int m = 0; m < 4; ++m) {
            acc[m][0] = (f32x4){b2_0, b2_0, b2_0, b2_0};
            acc[m][1] = (f32x4){b2_1, b2_1, b2_1, b2_1};
        }
        #pragma unroll
        for (int m = 0; m < 4; ++m)
            #pragma unroll
            for (int k = 0; k < 4; ++k) {
                short8 a = *(const short8*)&se[swz(m * 16 + (lane & 15), k * 32 + koff)];
                acc[m][0] = MFMA16(a, wfM[0][k], acc[m][0]);
                acc[m][1] = MFMA16(a, wfM[1][k], acc[m][1]);
            }

        // -- agg partial: Sum over this tile's rows of s[., acol] (bf16 re-read)
        {
            float sacc = 0.f;
            #pragma unroll
            for (int r = 0; r < 32; ++r)
                sacc += bf2f(se[swz(agrp * 32 + r, acol)]);
            aggp += sacc;
        }

        // -- coord weights: w = silu(c1) . cW2 (this wave's 32-col slice)
        #pragma unroll
        for (int m = 0; m < 4; ++m)
            #pragma unroll
            for (int reg = 0; reg < 4; ++reg) {
                float v = silu_f(acc[m][0][reg]) * cw2_0
                        + silu_f(acc[m][1][reg]) * cw2_1;
                v += __shfl_xor(v, 1); v += __shfl_xor(v, 2);
                v += __shfl_xor(v, 4); v += __shfl_xor(v, 8);
                if ((lane & 15) == 0)
                    warr[par][wave][m * 16 + (lane >> 4) * 4 + reg] = v;
            }
        __syncthreads();                                   // Bar2: warr/cdp ready, se free

        // -- coord accumulation: wave w handles rows w*16..w*16+15 (parity-safe)
        if (lane < 16) {
            const int row = wave * 16 + lane;
            const float w = warr[par][0][row] + warr[par][1][row]
                          + warr[par][2][row] + warr[par][3][row] + cb2v;
            cax += w * cdp[par][0][row];
            cay += w * cdp[par][1][row];
            caz += w * cdp[par][2][row];
        }
    }

    // ---- flush agg partials and coord sums
    aggw[agrp][acol] = aggp;
    {
        float sx = cax, sy = cay, sz = caz;
        sx += __shfl_xor(sx, 1); sy += __shfl_xor(sy, 1); sz += __shfl_xor(sz, 1);
        sx += __shfl_xor(sx, 2); sy += __shfl_xor(sy, 2); sz += __shfl_xor(sz, 2);
        sx += __shfl_xor(sx, 4); sy += __shfl_xor(sy, 4); sz += __shfl_xor(sz, 4);
        sx += __shfl_xor(sx, 8); sy += __shfl_xor(sy, 8); sz += __shfl_xor(sz, 8);
        if (lane == 0) { cred[wave][0] = sx; cred[wave][1] = sy; cred[wave][2] = sz; }
    }
    __syncthreads();
    if (tid < 128) aggs[tid] = aggw[0][tid] + aggw[1][tid];   // Sum_j s[j][tid]
    if (tid == 0) {
        const float sx = cred[0][0] + cred[1][0] + cred[2][0] + cred[3][0];
        const float sy = cred[0][1] + cred[1][1] + cred[2][1] + cred[3][1];
        const float sz = cred[0][2] + cred[1][2] + cred[2][2] + cred[3][2];
        out_coord[node * 3 + 0] = cix + sx * (1.f / 512.f);
        out_coord[node * 3 + 1] = ciy + sy * (1.f / 512.f);
        out_coord[node * 3 + 2] = ciz + sz * (1.f / 512.f);
    }
    __syncthreads();
    // ---- aggregated[c'] = (Sum_j s @ eW2)[c']/512 + eb2[c']
    if (tid < 128) {
        float acc = 0.f;
        #pragma unroll 4
        for (int c = 0; c < 128; ++c) acc += aggs[c] * eW2[c * 128 + tid];
        aggh[tid] = acc * (1.f / 512.f) + eb2[tid];
    }
    __syncthreads();
    // ---- node MLP
    if (tid < 128) {
        float acc = nb1[tid];
        #pragma unroll 4
        for (int k = 0; k < 128; ++k) acc += features[node * 128 + k] * nW1[k * 128 + tid];
        #pragma unroll 4
        for (int k = 0; k < 128; ++k) acc += aggh[k] * nW1[(128 + k) * 128 + tid];
        hbuf[tid] = silu_f(acc);
    }
    __syncthreads();
    if (tid < 128) {
        float acc = nb2[tid];
        #pragma unroll 4
        for (int k = 0; k < 128; ++k) acc += hbuf[k] * nW2[k * 128 + tid];
        out_feat[node * 128 + tid] = acc;
    }
}

extern "C" void kernel_launch(void* const* d_in, const int* in_sizes, int n_in,
                              void* d_out, int out_size, void* d_ws, size_t ws_size,
                              hipStream_t stream)
{
    const float* features = (const float*)d_in[0];
    const float* coords   = (const float*)d_in[1];
    const float* eW1 = (const float*)d_in[2];
    const float* eb1 = (const float*)d_in[3];
    const float* eW2 = (const float*)d_in[4];
    const float* eb2 = (const float*)d_in[5];
    const float* nW1 = (const float*)d_in[6];
    const float* nb1 = (const float*)d_in[7];
    const float* nW2 = (const float*)d_in[8];
    const float* nb2 = (const float*)d_in[9];
    const float* cW1 = (const float*)d_in[10];
    const float* cb1 = (const float*)d_in[11];
    const float* cW2 = (const float*)d_in[12];
    const float* cb2 = (const float*)d_in[13];

    float* out = (float*)d_out;
    float* out_feat  = out;                       // (2,512,128)
    float* out_coord = out + 2 * 512 * 128;       // (2,512,3)

    float* Abuf    = (float*)d_ws;                // 131072 f32
    float* Bbuf    = Abuf + 2 * 512 * 128;        // 131072 f32
    float* Mws     = Bbuf + 2 * 512 * 128;        // 16384 f32
    float* bias2ws = Mws + 128 * 128;             // 128 f32

    egnn_pre<<<1024, 256, 0, stream>>>(features, eW1, eb1, Abuf, Bbuf);
    egnn_wprep<<<129, 128, 0, stream>>>(eW2, cW1, eb2, cb1, Mws, bias2ws);
    egnn_main<<<1024, 256, 0, stream>>>(features, coords, eW1, eW2, eb2,
                                        nW1, nb1, nW2, nb2, cW2, cb2,
                                        Abuf, Bbuf, Mws, bias2ws,
                                        out_feat, out_coord);
}

// Round 7
// 204.372 us; speedup vs baseline: 1.4714x; 1.4714x over previous
//
#include <hip/hip_runtime.h>
#include <hip/hip_bf16.h>
#include <math.h>

// EquivariantGraphConv fused kernel for MI355X (gfx950).
// B=2, N=512, D=HID=OUT=128.
//
// Structure: edge MLP factorized -- h1 = aw_i + Bbuf_j + dist*wd (per-node
// precompute), and since there is no activation between the two edge GEMMs,
// c1 = s@M + bias2 with M = eW2@cW1 precomputed (bf16, transposed).
// Aggregation via column sums of s: Sum_j edge_hidden = (Sum_j s)@eW2 + 512*eb2.
//
// Round 6 -> 7: round-6's launch_bounds(256,4)+reg-prefetch made the allocator
// cap at 64 VGPR and spill 367 MB (prefetch became a scratch round-trip).
// Reverted to the round-5 no-prefetch loop (84 VGPR, no spill, 153us) and
// attacked the latency-bound profile (MfmaUtil 4.4%, VALUBusy 30%, occ 24%)
// structurally:
//  (1) j-loop split across 2 blocks/node (grid 2048, 4 tiles each): 2x TLP,
//      half the per-block barrier chain; partials in d_ws + egnn_post combine.
//  (2) agg re-read via 4x ds_read_b128 + 8 reg partials (was 32x ds_read_u16).
//  (3) M stored transposed bf16 -> weight fragments load as 8 dwordx4/thread
//      (was 64 scalar f32 loads).

typedef float f32x4 __attribute__((ext_vector_type(4)));
typedef short short8 __attribute__((ext_vector_type(8)));

#define MFMA16(a, b, c) __builtin_amdgcn_mfma_f32_16x16x32_bf16((a), (b), (c), 0, 0, 0)

__device__ __forceinline__ short f2bf(float x) {
    __hip_bfloat16 h = __float2bfloat16(x);
    union { __hip_bfloat16 h; short s; } v; v.h = h;
    return v.s;
}
__device__ __forceinline__ float bf2f(short s) {
    union { unsigned u; float f; } v; v.u = ((unsigned)(unsigned short)s) << 16;
    return v.f;
}
__device__ __forceinline__ float silu_f(float x) {
    return x * __builtin_amdgcn_rcpf(1.0f + __expf(-x));
}

// XOR swizzle for [rows][128] bf16 LDS tiles (G4: break stride-256B conflicts).
__device__ __forceinline__ int swz(int row, int col) {
    int byte = (row << 8) | (col << 1);
    byte ^= (row & 7) << 4;
    return byte >> 1;  // bf16-element index
}

// ---------- precompute: Abuf = feat @ eW1[0:128] + eb1 ; Bbuf = feat @ eW1[128:256]
__global__ void egnn_pre(const float* __restrict__ feat, const float* __restrict__ eW1,
                         const float* __restrict__ eb1,
                         float* __restrict__ Abuf, float* __restrict__ Bbuf) {
    __shared__ float f[128];
    const int nid = blockIdx.x;
    const int t = threadIdx.x;   // 256 threads
    if (t < 128) f[t] = feat[nid * 128 + t];
    __syncthreads();
    const int col  = t & 127;
    const int half = t >> 7;
    const float* W = eW1 + (size_t)half * 128 * 128 + col;
    float acc = half ? 0.f : eb1[col];
    #pragma unroll 8
    for (int k = 0; k < 128; ++k) acc += f[k] * W[(size_t)k * 128];
    if (half == 0) Abuf[nid * 128 + col] = acc;
    else           Bbuf[nid * 128 + col] = acc;
}

// ---------- precompute: MbfT[c][a] = bf16((eW2@cW1)[a][c]); bias2 = eb2@cW1 + cb1
__global__ void egnn_wprep(const float* __restrict__ eW2, const float* __restrict__ cW1,
                           const float* __restrict__ eb2, const float* __restrict__ cb1,
                           unsigned short* __restrict__ MbfT, float* __restrict__ bias2ws) {
    const int a = blockIdx.x;      // 0..128 (128 => bias2)
    const int c = threadIdx.x;     // 128 threads
    if (a < 128) {
        float acc = 0.f;
        #pragma unroll 8
        for (int h = 0; h < 128; ++h) acc += eW2[a * 128 + h] * cW1[h * 128 + c];
        MbfT[c * 128 + a] = (unsigned short)f2bf(acc);
    } else {
        float acc = cb1[c];
        #pragma unroll 8
        for (int h = 0; h < 128; ++h) acc += eb2[h] * cW1[h * 128 + c];
        bias2ws[c] = acc;
    }
}

// ---------- main: one block per (node, j-half); 4 j-tiles of 64 each
__global__ void __launch_bounds__(256, 2) egnn_main(
    const float* __restrict__ coords, const float* __restrict__ eW1,
    const float* __restrict__ cW2, const float* __restrict__ cb2,
    const float* __restrict__ Abuf, const float* __restrict__ Bbuf,
    const unsigned short* __restrict__ MbfT, const float* __restrict__ bias2ws,
    float* __restrict__ aggpart, float* __restrict__ coordpart)
{
    constexpr int Nn = 512;
    __shared__ __align__(16) short se[64 * 128];            // 16 KB s-tile
    __shared__ float aw[128], wd[128];
    __shared__ float cdp[2][3][64];                         // parity-buffered coord diffs
    __shared__ float warr[2][4][64];                        // parity-buffered w partials
    __shared__ float aggred[16][128];                       // agg partial reduce
    __shared__ float cred[4][3];
    __shared__ float ci3[3];

    const int tid  = threadIdx.x;
    const int lane = tid & 63;
    const int wave = tid >> 6;
    const int bid  = blockIdx.x;
    const int node = bid >> 1;         // b*512 + i
    const int half = bid & 1;
    const int b    = node >> 9;

    if (tid < 128) {
        aw[tid] = Abuf[node * 128 + tid];      // includes eb1
        wd[tid] = eW1[256 * 128 + tid];        // distance row of eW1
    }
    if (tid == 0) {
        ci3[0] = coords[node * 3 + 0];
        ci3[1] = coords[node * 3 + 1];
        ci3[2] = coords[node * 3 + 2];
    }

    // ---- M^T fragments: 8 x dwordx4 loads from bf16 MbfT (L2-resident)
    const int cfrag = wave * 32 + (lane & 15);
    const int koff  = (lane >> 4) * 8;
    short8 wfM[2][4];
    #pragma unroll
    for (int n2 = 0; n2 < 2; ++n2)
        #pragma unroll
        for (int k = 0; k < 4; ++k)
            wfM[n2][k] = *(const short8*)&MbfT[(size_t)(cfrag + n2 * 16) * 128 + k * 32 + koff];
    __syncthreads();

    const float b2_0  = bias2ws[cfrag], b2_1 = bias2ws[cfrag + 16];
    const float cw2_0 = cW2[cfrag],     cw2_1 = cW2[cfrag + 16];
    const float cb2v  = cb2[0];
    const float cix = ci3[0], ciy = ci3[1], ciz = ci3[2];

    const int jr = tid >> 2, cb = (tid & 3) * 32;   // build mapping
    const int rg = tid >> 4, c8 = (tid & 15) * 8;   // agg mapping

    float ap[8];                        // per-thread agg col partials
    #pragma unroll
    for (int q = 0; q < 8; ++q) ap[q] = 0.f;
    float cax = 0.f, cay = 0.f, caz = 0.f;

    for (int t = 0; t < 4; ++t) {
        const int par = t & 1;
        // -- build: s = silu(aw + Bbuf_j + dist*wd) -> bf16 LDS
        {
            const int j = half * 256 + t * 64 + jr;
            const float dx = cix - coords[(b * Nn + j) * 3 + 0];
            const float dy = ciy - coords[(b * Nn + j) * 3 + 1];
            const float dz = ciz - coords[(b * Nn + j) * 3 + 2];
            const float dj = sqrtf(dx * dx + dy * dy + dz * dz + 1e-8f);
            if ((tid & 3) == 0) {
                cdp[par][0][jr] = dx; cdp[par][1][jr] = dy; cdp[par][2][jr] = dz;
            }
            const float* Bj = Bbuf + (size_t)(b * Nn + j) * 128 + cb;
            #pragma unroll
            for (int cc = 0; cc < 32; cc += 8) {
                f32x4 x0 = *(const f32x4*)(Bj + cc);
                f32x4 x1 = *(const f32x4*)(Bj + cc + 4);
                short8 v;
                #pragma unroll
                for (int r = 0; r < 4; ++r) {
                    const int c = cb + cc + r;
                    v[r] = f2bf(silu_f(aw[c] + x0[r] + dj * wd[c]));
                }
                #pragma unroll
                for (int r = 0; r < 4; ++r) {
                    const int c = cb + cc + 4 + r;
                    v[4 + r] = f2bf(silu_f(aw[c] + x1[r] + dj * wd[c]));
                }
                *(short8*)&se[swz(jr, cb + cc)] = v;
            }
        }
        __syncthreads();                                   // Bar1: tile ready

        // -- GEMM: c1 = s @ M + bias2 (acc init = bias2)
        f32x4 acc[4][2];
        #pragma unroll
        for (int m = 0; m < 4; ++m) {
            acc[m][0] = (f32x4){b2_0, b2_0, b2_0, b2_0};
            acc[m][1] = (f32x4){b2_1, b2_1, b2_1, b2_1};
        }
        #pragma unroll
        for (int m = 0; m < 4; ++m)
            #pragma unroll
            for (int k = 0; k < 4; ++k) {
                short8 a = *(const short8*)&se[swz(m * 16 + (lane & 15), k * 32 + koff)];
                acc[m][0] = MFMA16(a, wfM[0][k], acc[m][0]);
                acc[m][1] = MFMA16(a, wfM[1][k], acc[m][1]);
            }

        // -- agg partials: rows rg*4..rg*4+3, cols c8..c8+7 (4 x ds_read_b128)
        #pragma unroll
        for (int r = 0; r < 4; ++r) {
            short8 v = *(const short8*)&se[swz(rg * 4 + r, c8)];
            #pragma unroll
            for (int q = 0; q < 8; ++q) ap[q] += bf2f(v[q]);
        }

        // -- coord weights: w = silu(c1) . cW2 (this wave's 32-col slice)
        #pragma unroll
        for (int m = 0; m < 4; ++m)
            #pragma unroll
            for (int reg = 0; reg < 4; ++reg) {
                float v = silu_f(acc[m][0][reg]) * cw2_0
                        + silu_f(acc[m][1][reg]) * cw2_1;
                v += __shfl_xor(v, 1); v += __shfl_xor(v, 2);
                v += __shfl_xor(v, 4); v += __shfl_xor(v, 8);
                if ((lane & 15) == 0)
                    warr[par][wave][m * 16 + (lane >> 4) * 4 + reg] = v;
            }
        __syncthreads();                                   // Bar2: warr/cdp ready, se free

        // -- coord accumulation: wave w handles rows w*16..w*16+15 (parity-safe)
        if (lane < 16) {
            const int row = wave * 16 + lane;
            const float w = warr[par][0][row] + warr[par][1][row]
                          + warr[par][2][row] + warr[par][3][row] + cb2v;
            cax += w * cdp[par][0][row];
            cay += w * cdp[par][1][row];
            caz += w * cdp[par][2][row];
        }
    }

    // ---- flush agg partials (16 row-groups x 128 cols) and coord sums
    #pragma unroll
    for (int q = 0; q < 8; ++q) aggred[rg][c8 + q] = ap[q];
    {
        float sx = cax, sy = cay, sz = caz;
        sx += __shfl_xor(sx, 1); sy += __shfl_xor(sy, 1); sz += __shfl_xor(sz, 1);
        sx += __shfl_xor(sx, 2); sy += __shfl_xor(sy, 2); sz += __shfl_xor(sz, 2);
        sx += __shfl_xor(sx, 4); sy += __shfl_xor(sy, 4); sz += __shfl_xor(sz, 4);
        sx += __shfl_xor(sx, 8); sy += __shfl_xor(sy, 8); sz += __shfl_xor(sz, 8);
        if (lane == 0) { cred[wave][0] = sx; cred[wave][1] = sy; cred[wave][2] = sz; }
    }
    __syncthreads();
    if (tid < 128) {
        float s = 0.f;
        #pragma unroll
        for (int g = 0; g < 16; ++g) s += aggred[g][tid];
        aggpart[(size_t)bid * 128 + tid] = s;
    }
    if (tid < 3) {
        coordpart[bid * 3 + tid] = cred[0][tid] + cred[1][tid] + cred[2][tid] + cred[3][tid];
    }
}

// ---------- combine + epilogue: one block per node, 128 threads
__global__ void egnn_post(
    const float* __restrict__ features, const float* __restrict__ coords,
    const float* __restrict__ eW2, const float* __restrict__ eb2,
    const float* __restrict__ nW1, const float* __restrict__ nb1,
    const float* __restrict__ nW2, const float* __restrict__ nb2,
    const float* __restrict__ aggpart, const float* __restrict__ coordpart,
    float* __restrict__ out_feat, float* __restrict__ out_coord)
{
    __shared__ float aggs[128], aggh[128], hbuf[128], fi[128];
    const int node = blockIdx.x;
    const int tid  = threadIdx.x;   // 128

    aggs[tid] = aggpart[(size_t)(node * 2) * 128 + tid]
              + aggpart[(size_t)(node * 2 + 1) * 128 + tid];
    fi[tid]   = features[node * 128 + tid];
    __syncthreads();
    // aggregated = (Sum_j s @ eW2)/512 + eb2
    {
        float acc = 0.f;
        #pragma unroll 4
        for (int c = 0; c < 128; ++c) acc += aggs[c] * eW2[c * 128 + tid];
        aggh[tid] = acc * (1.f / 512.f) + eb2[tid];
    }
    if (tid < 3) {
        out_coord[node * 3 + tid] = coords[node * 3 + tid]
            + (coordpart[(node * 2) * 3 + tid] + coordpart[(node * 2 + 1) * 3 + tid])
              * (1.f / 512.f);
    }
    __syncthreads();
    // node MLP
    {
        float acc = nb1[tid];
        #pragma unroll 4
        for (int k = 0; k < 128; ++k) acc += fi[k] * nW1[k * 128 + tid];
        #pragma unroll 4
        for (int k = 0; k < 128; ++k) acc += aggh[k] * nW1[(128 + k) * 128 + tid];
        hbuf[tid] = silu_f(acc);
    }
    __syncthreads();
    {
        float acc = nb2[tid];
        #pragma unroll 4
        for (int k = 0; k < 128; ++k) acc += hbuf[k] * nW2[k * 128 + tid];
        out_feat[node * 128 + tid] = acc;
    }
}

extern "C" void kernel_launch(void* const* d_in, const int* in_sizes, int n_in,
                              void* d_out, int out_size, void* d_ws, size_t ws_size,
                              hipStream_t stream)
{
    const float* features = (const float*)d_in[0];
    const float* coords   = (const float*)d_in[1];
    const float* eW1 = (const float*)d_in[2];
    const float* eb1 = (const float*)d_in[3];
    const float* eW2 = (const float*)d_in[4];
    const float* eb2 = (const float*)d_in[5];
    const float* nW1 = (const float*)d_in[6];
    const float* nb1 = (const float*)d_in[7];
    const float* nW2 = (const float*)d_in[8];
    const float* nb2 = (const float*)d_in[9];
    const float* cW1 = (const float*)d_in[10];
    const float* cb1 = (const float*)d_in[11];
    const float* cW2 = (const float*)d_in[12];
    const float* cb2 = (const float*)d_in[13];

    float* out = (float*)d_out;
    float* out_feat  = out;                       // (2,512,128)
    float* out_coord = out + 2 * 512 * 128;       // (2,512,3)

    float* Abuf      = (float*)d_ws;                    // 131072 f32
    float* Bbuf      = Abuf + 2 * 512 * 128;            // 131072 f32
    unsigned short* MbfT = (unsigned short*)(Bbuf + 2 * 512 * 128);  // 16384 u16
    float* bias2ws   = (float*)(MbfT + 128 * 128);      // 128 f32
    float* aggpart   = bias2ws + 128;                   // 2048*128 f32 (1 MB)
    float* coordpart = aggpart + 2048 * 128;            // 2048*3 f32

    egnn_pre<<<1024, 256, 0, stream>>>(features, eW1, eb1, Abuf, Bbuf);
    egnn_wprep<<<129, 128, 0, stream>>>(eW2, cW1, eb2, cb1, MbfT, bias2ws);
    egnn_main<<<2048, 256, 0, stream>>>(coords, eW1, cW2, cb2,
                                        Abuf, Bbuf, MbfT, bias2ws,
                                        aggpart, coordpart);
    egnn_post<<<1024, 128, 0, stream>>>(features, coords, eW2, eb2,
                                        nW1, nb1, nW2, nb2,
                                        aggpart, coordpart, out_feat, out_coord);
}

// Round 8
// 184.916 us; speedup vs baseline: 1.6262x; 1.1052x over previous
//
#include <hip/hip_runtime.h>
#include <hip/hip_bf16.h>
#include <math.h>

// EquivariantGraphConv fused kernel for MI355X (gfx950).
// B=2, N=512, D=HID=OUT=128.
//
// Structure: edge MLP factorized -- h1 = aw_i + Bbuf_j + dist*wd (per-node
// precompute), and since there is no activation between the two edge GEMMs,
// c1 = s@M + bias2 with M = eW2@cW1 precomputed (bf16, transposed).
// Aggregation via column sums of s: Sum_j edge_hidden = (Sum_j s)@eW2 + 512*eb2.
//
// Round 7 -> 8: main=87us but total=204us; (total-main) across rounds is
// ~75us at 2-3 launches (+39 at 4) while aux arithmetic is ~1-5us -> the gap
// is per-dispatch overhead, not aux work. Changes:
//  (1) fuse wprep into pre (4 launches -> 3, block-range split, grid 1089).
//  (2) main grid 2048 -> 4096 (4 blocks/node, 2 j-tiles each): per-block
//      barrier chain halved, 2x TLP. Node partials combined via f32
//      atomicAdd (device-scope; zeroed by prew each launch).
//  (3) post: 256 threads, split-k across wave pairs (halved FMA chains).

typedef float f32x4 __attribute__((ext_vector_type(4)));
typedef short short8 __attribute__((ext_vector_type(8)));

#define MFMA16(a, b, c) __builtin_amdgcn_mfma_f32_16x16x32_bf16((a), (b), (c), 0, 0, 0)

__device__ __forceinline__ short f2bf(float x) {
    __hip_bfloat16 h = __float2bfloat16(x);
    union { __hip_bfloat16 h; short s; } v; v.h = h;
    return v.s;
}
__device__ __forceinline__ float bf2f(short s) {
    union { unsigned u; float f; } v; v.u = ((unsigned)(unsigned short)s) << 16;
    return v.f;
}
__device__ __forceinline__ float silu_f(float x) {
    return x * __builtin_amdgcn_rcpf(1.0f + __expf(-x));
}

// XOR swizzle for [rows][128] bf16 LDS tiles (G4: break stride-256B conflicts).
__device__ __forceinline__ int swz(int row, int col) {
    int byte = (row << 8) | (col << 1);
    byte ^= (row & 7) << 4;
    return byte >> 1;  // bf16-element index
}

// ---------- fused precompute, grid 1089 x 256:
// blocks [0,1024): Abuf/Bbuf per node + zero the atomic partial buffers
// blocks [1024,1089): M = eW2@cW1 -> MbfT (bf16, transposed), bias2
__global__ void egnn_prew(const float* __restrict__ feat, const float* __restrict__ eW1,
                          const float* __restrict__ eb1,
                          const float* __restrict__ eW2, const float* __restrict__ cW1,
                          const float* __restrict__ eb2, const float* __restrict__ cb1,
                          float* __restrict__ Abuf, float* __restrict__ Bbuf,
                          unsigned short* __restrict__ MbfT, float* __restrict__ bias2ws,
                          float* __restrict__ aggpart, float* __restrict__ coordpart) {
    const int bid = blockIdx.x;
    const int t = threadIdx.x;   // 256
    if (bid < 1024) {
        __shared__ float f[128];
        if (t < 128) f[t] = feat[bid * 128 + t];
        __syncthreads();
        const int col  = t & 127;
        const int half = t >> 7;
        const float* W = eW1 + (size_t)half * 128 * 128 + col;
        float acc = half ? 0.f : eb1[col];
        #pragma unroll 8
        for (int k = 0; k < 128; ++k) acc += f[k] * W[(size_t)k * 128];
        if (half == 0) Abuf[bid * 128 + col] = acc;
        else           Bbuf[bid * 128 + col] = acc;
        if (t < 128) aggpart[(size_t)bid * 128 + t] = 0.f;
        if (t < 3)   coordpart[bid * 3 + t] = 0.f;
    } else {
        const int idx = (bid - 1024) * 2 + (t >> 7);   // 0..129
        const int c = t & 127;
        if (idx < 128) {
            float acc = 0.f;
            #pragma unroll 8
            for (int h = 0; h < 128; ++h) acc += eW2[idx * 128 + h] * cW1[h * 128 + c];
            MbfT[c * 128 + idx] = (unsigned short)f2bf(acc);
        } else if (idx == 128) {
            float acc = cb1[c];
            #pragma unroll 8
            for (int h = 0; h < 128; ++h) acc += eb2[h] * cW1[h * 128 + c];
            bias2ws[c] = acc;
        }
    }
}

// ---------- main: one block per (node, j-quarter); 2 j-tiles of 64 each
__global__ void __launch_bounds__(256, 2) egnn_main(
    const float* __restrict__ coords, const float* __restrict__ eW1,
    const float* __restrict__ cW2, const float* __restrict__ cb2,
    const float* __restrict__ Abuf, const float* __restrict__ Bbuf,
    const unsigned short* __restrict__ MbfT, const float* __restrict__ bias2ws,
    float* __restrict__ aggpart, float* __restrict__ coordpart)
{
    constexpr int Nn = 512;
    __shared__ __align__(16) short se[64 * 128];            // 16 KB s-tile
    __shared__ float aw[128], wd[128];
    __shared__ float cdp[2][3][64];                         // parity-buffered coord diffs
    __shared__ float warr[2][4][64];                        // parity-buffered w partials
    __shared__ float aggred[16][128];                       // agg partial reduce
    __shared__ float cred[4][3];
    __shared__ float ci3[3];

    const int tid  = threadIdx.x;
    const int lane = tid & 63;
    const int wave = tid >> 6;
    const int bid  = blockIdx.x;
    const int node = bid >> 2;         // b*512 + i
    const int quad = bid & 3;
    const int b    = node >> 9;

    if (tid < 128) {
        aw[tid] = Abuf[node * 128 + tid];      // includes eb1
        wd[tid] = eW1[256 * 128 + tid];        // distance row of eW1
    }
    if (tid == 0) {
        ci3[0] = coords[node * 3 + 0];
        ci3[1] = coords[node * 3 + 1];
        ci3[2] = coords[node * 3 + 2];
    }

    // ---- M^T fragments: 8 x dwordx4 loads from bf16 MbfT (L2-resident)
    const int cfrag = wave * 32 + (lane & 15);
    const int koff  = (lane >> 4) * 8;
    short8 wfM[2][4];
    #pragma unroll
    for (int n2 = 0; n2 < 2; ++n2)
        #pragma unroll
        for (int k = 0; k < 4; ++k)
            wfM[n2][k] = *(const short8*)&MbfT[(size_t)(cfrag + n2 * 16) * 128 + k * 32 + koff];
    __syncthreads();

    const float b2_0  = bias2ws[cfrag], b2_1 = bias2ws[cfrag + 16];
    const float cw2_0 = cW2[cfrag],     cw2_1 = cW2[cfrag + 16];
    const float cb2v  = cb2[0];
    const float cix = ci3[0], ciy = ci3[1], ciz = ci3[2];

    const int jr = tid >> 2, cb = (tid & 3) * 32;   // build mapping
    const int rg = tid >> 4, c8 = (tid & 15) * 8;   // agg mapping

    float ap[8];                        // per-thread agg col partials
    #pragma unroll
    for (int q = 0; q < 8; ++q) ap[q] = 0.f;
    float cax = 0.f, cay = 0.f, caz = 0.f;

    for (int t = 0; t < 2; ++t) {
        const int par = t & 1;
        // -- build: s = silu(aw + Bbuf_j + dist*wd) -> bf16 LDS
        {
            const int j = quad * 128 + t * 64 + jr;
            const float dx = cix - coords[(b * Nn + j) * 3 + 0];
            const float dy = ciy - coords[(b * Nn + j) * 3 + 1];
            const float dz = ciz - coords[(b * Nn + j) * 3 + 2];
            const float dj = sqrtf(dx * dx + dy * dy + dz * dz + 1e-8f);
            if ((tid & 3) == 0) {
                cdp[par][0][jr] = dx; cdp[par][1][jr] = dy; cdp[par][2][jr] = dz;
            }
            const float* Bj = Bbuf + (size_t)(b * Nn + j) * 128 + cb;
            #pragma unroll
            for (int cc = 0; cc < 32; cc += 8) {
                f32x4 x0 = *(const f32x4*)(Bj + cc);
                f32x4 x1 = *(const f32x4*)(Bj + cc + 4);
                short8 v;
                #pragma unroll
                for (int r = 0; r < 4; ++r) {
                    const int c = cb + cc + r;
                    v[r] = f2bf(silu_f(aw[c] + x0[r] + dj * wd[c]));
                }
                #pragma unroll
                for (int r = 0; r < 4; ++r) {
                    const int c = cb + cc + 4 + r;
                    v[4 + r] = f2bf(silu_f(aw[c] + x1[r] + dj * wd[c]));
                }
                *(short8*)&se[swz(jr, cb + cc)] = v;
            }
        }
        __syncthreads();                                   // Bar1: tile ready

        // -- GEMM: c1 = s @ M + bias2 (acc init = bias2)
        f32x4 acc[4][2];
        #pragma unroll
        for (int m = 0; m < 4; ++m) {
            acc[m][0] = (f32x4){b2_0, b2_0, b2_0, b2_0};
            acc[m][1] = (f32x4){b2_1, b2_1, b2_1, b2_1};
        }
        #pragma unroll
        for (int m = 0; m < 4; ++m)
            #pragma unroll
            for (int k = 0; k < 4; ++k) {
                short8 a = *(const short8*)&se[swz(m * 16 + (lane & 15), k * 32 + koff)];
                acc[m][0] = MFMA16(a, wfM[0][k], acc[m][0]);
                acc[m][1] = MFMA16(a, wfM[1][k], acc[m][1]);
            }

        // -- agg partials: rows rg*4..rg*4+3, cols c8..c8+7 (4 x ds_read_b128)
        #pragma unroll
        for (int r = 0; r < 4; ++r) {
            short8 v = *(const short8*)&se[swz(rg * 4 + r, c8)];
            #pragma unroll
            for (int q = 0; q < 8; ++q) ap[q] += bf2f(v[q]);
        }

        // -- coord weights: w = silu(c1) . cW2 (this wave's 32-col slice)
        #pragma unroll
        for (int m = 0; m < 4; ++m)
            #pragma unroll
            for (int reg = 0; reg < 4; ++reg) {
                float v = silu_f(acc[m][0][reg]) * cw2_0
                        + silu_f(acc[m][1][reg]) * cw2_1;
                v += __shfl_xor(v, 1); v += __shfl_xor(v, 2);
                v += __shfl_xor(v, 4); v += __shfl_xor(v, 8);
                if ((lane & 15) == 0)
                    warr[par][wave][m * 16 + (lane >> 4) * 4 + reg] = v;
            }
        __syncthreads();                                   // Bar2: warr/cdp ready, se free

        // -- coord accumulation: wave w handles rows w*16..w*16+15 (parity-safe)
        if (lane < 16) {
            const int row = wave * 16 + lane;
            const float w = warr[par][0][row] + warr[par][1][row]
                          + warr[par][2][row] + warr[par][3][row] + cb2v;
            cax += w * cdp[par][0][row];
            cay += w * cdp[par][1][row];
            caz += w * cdp[par][2][row];
        }
    }

    // ---- flush agg partials (16 row-groups x 128 cols) and coord sums
    #pragma unroll
    for (int q = 0; q < 8; ++q) aggred[rg][c8 + q] = ap[q];
    {
        float sx = cax, sy = cay, sz = caz;
        sx += __shfl_xor(sx, 1); sy += __shfl_xor(sy, 1); sz += __shfl_xor(sz, 1);
        sx += __shfl_xor(sx, 2); sy += __shfl_xor(sy, 2); sz += __shfl_xor(sz, 2);
        sx += __shfl_xor(sx, 4); sy += __shfl_xor(sy, 4); sz += __shfl_xor(sz, 4);
        sx += __shfl_xor(sx, 8); sy += __shfl_xor(sy, 8); sz += __shfl_xor(sz, 8);
        if (lane == 0) { cred[wave][0] = sx; cred[wave][1] = sy; cred[wave][2] = sz; }
    }
    __syncthreads();
    if (tid < 128) {
        float s = 0.f;
        #pragma unroll
        for (int g = 0; g < 16; ++g) s += aggred[g][tid];
        atomicAdd(&aggpart[(size_t)node * 128 + tid], s);
    }
    if (tid < 3) {
        atomicAdd(&coordpart[node * 3 + tid],
                  cred[0][tid] + cred[1][tid] + cred[2][tid] + cred[3][tid]);
    }
}

// ---------- epilogue: one block per node, 256 threads (split-k across wave pairs)
__global__ void egnn_post(
    const float* __restrict__ features, const float* __restrict__ coords,
    const float* __restrict__ eW2, const float* __restrict__ eb2,
    const float* __restrict__ nW1, const float* __restrict__ nb1,
    const float* __restrict__ nW2, const float* __restrict__ nb2,
    const float* __restrict__ aggpart, const float* __restrict__ coordpart,
    float* __restrict__ out_feat, float* __restrict__ out_coord)
{
    __shared__ float aggs[128], aggh[128], hbuf[128], fi[128], part[128];
    const int node = blockIdx.x;
    const int tid  = threadIdx.x;   // 256
    const int c = tid & 127, g = tid >> 7;   // g uniform per wave-pair

    if (tid < 128) {
        aggs[tid] = aggpart[(size_t)node * 128 + tid];
        fi[tid]   = features[node * 128 + tid];
    }
    if (tid < 3)
        out_coord[node * 3 + tid] = coords[node * 3 + tid]
                                  + coordpart[node * 3 + tid] * (1.f / 512.f);
    __syncthreads();
    // aggregated = (Sum_j s @ eW2)/512 + eb2, reduction split over g
    {
        float acc = 0.f;
        #pragma unroll 8
        for (int k = g * 64; k < g * 64 + 64; ++k) acc += aggs[k] * eW2[k * 128 + c];
        if (g == 1) part[c] = acc;
        __syncthreads();
        if (g == 0) aggh[c] = (acc + part[c]) * (1.f / 512.f) + eb2[c];
        __syncthreads();
    }
    // node MLP layer 1: g=0 does features-half, g=1 does agg-half of nW1
    {
        float acc = (g == 0) ? nb1[c] : 0.f;
        const float* src = (g == 0) ? fi : aggh;
        const float* W = nW1 + (size_t)(g << 7) * 128 + c;
        #pragma unroll 8
        for (int k = 0; k < 128; ++k) acc += src[k] * W[(size_t)k * 128];
        if (g == 1) part[c] = acc;
        __syncthreads();
        if (g == 0) hbuf[c] = silu_f(acc + part[c]);
        __syncthreads();
    }
    // node MLP layer 2, split-k over g
    {
        float acc = (g == 0) ? nb2[c] : 0.f;
        #pragma unroll 8
        for (int k = g * 64; k < g * 64 + 64; ++k) acc += hbuf[k] * nW2[k * 128 + c];
        if (g == 1) part[c] = acc;
        __syncthreads();
        if (g == 0) out_feat[node * 128 + c] = acc + part[c];
    }
}

extern "C" void kernel_launch(void* const* d_in, const int* in_sizes, int n_in,
                              void* d_out, int out_size, void* d_ws, size_t ws_size,
                              hipStream_t stream)
{
    const float* features = (const float*)d_in[0];
    const float* coords   = (const float*)d_in[1];
    const float* eW1 = (const float*)d_in[2];
    const float* eb1 = (const float*)d_in[3];
    const float* eW2 = (const float*)d_in[4];
    const float* eb2 = (const float*)d_in[5];
    const float* nW1 = (const float*)d_in[6];
    const float* nb1 = (const float*)d_in[7];
    const float* nW2 = (const float*)d_in[8];
    const float* nb2 = (const float*)d_in[9];
    const float* cW1 = (const float*)d_in[10];
    const float* cb1 = (const float*)d_in[11];
    const float* cW2 = (const float*)d_in[12];
    const float* cb2 = (const float*)d_in[13];

    float* out = (float*)d_out;
    float* out_feat  = out;                       // (2,512,128)
    float* out_coord = out + 2 * 512 * 128;       // (2,512,3)

    float* Abuf      = (float*)d_ws;                    // 131072 f32
    float* Bbuf      = Abuf + 2 * 512 * 128;            // 131072 f32
    unsigned short* MbfT = (unsigned short*)(Bbuf + 2 * 512 * 128);  // 16384 u16
    float* bias2ws   = (float*)(MbfT + 128 * 128);      // 128 f32
    float* aggpart   = bias2ws + 128;                   // 1024*128 f32
    float* coordpart = aggpart + 1024 * 128;            // 1024*3 f32

    egnn_prew<<<1089, 256, 0, stream>>>(features, eW1, eb1, eW2, cW1, eb2, cb1,
                                        Abuf, Bbuf, MbfT, bias2ws, aggpart, coordpart);
    egnn_main<<<4096, 256, 0, stream>>>(coords, eW1, cW2, cb2,
                                        Abuf, Bbuf, MbfT, bias2ws,
                                        aggpart, coordpart);
    egnn_post<<<1024, 256, 0, stream>>>(features, coords, eW2, eb2,
                                        nW1, nb1, nW2, nb2,
                                        aggpart, coordpart, out_feat, out_coord);
}